// Round 7
// baseline (570.846 us; speedup 1.0000x reference)
//
#include <hip/hip_runtime.h>
#include <math.h>

// Round 15: persistent mega-kernel v2. R1's failure re-diagnosed as VGPR squeeze
// (launch_bounds(256,4) -> 64 VGPR, FETCH 420MB) not sync cost. This version:
// coop launch (co-residency guarantee, proven to run in R1) + hand-rolled
// atomic barrier (arrive + s_sleep spin + threadfence) + the UNMODIFIED R14
// deep GEMM bodies at launch_bounds(512,2) (measured 47us standalone).
// Grid 256 x 512thr x 128KB LDS = 1 block/CU. Mt overlaps X->f16 conversion.
// Stages: S1 Wsplit+WvT | S2 Mt(b<64) || X->f16(b>=64) | S3 T(b<128) || Vt |
//         S4 Sc | S5 softmax | S6 PV.  5 barriers.
// Fallback: R14 6-dispatch path (275us) if coop launch / attrs / ws_size fail.

typedef __bf16 bf16;
typedef _Float16 f16;
typedef __bf16 bf16x8 __attribute__((ext_vector_type(8)));
typedef __bf16 bf16x4 __attribute__((ext_vector_type(4)));
typedef _Float16 f16x4 __attribute__((ext_vector_type(4)));
typedef _Float16 f16x8 __attribute__((ext_vector_type(8)));
typedef float  f32x4  __attribute__((ext_vector_type(4)));

template<typename E> struct vec8_of;
template<> struct vec8_of<bf16> { using type = bf16x8; };
template<> struct vec8_of<f16>  { using type = f16x8; };

__device__ inline f32x4 mfma16(bf16x8 a, bf16x8 b, f32x4 c) {
    return __builtin_amdgcn_mfma_f32_16x16x32_bf16(a, b, c, 0, 0, 0);
}
__device__ inline f32x4 mfma16(f16x8 a, f16x8 b, f32x4 c) {
    return __builtin_amdgcn_mfma_f32_16x16x32_f16(a, b, c, 0, 0, 0);
}

#define AS1 __attribute__((address_space(1)))
#define AS3 __attribute__((address_space(3)))

template<typename E>
__device__ inline void async_load16(const E* g, void* l) {
    __builtin_amdgcn_global_load_lds((const AS1 unsigned int*)g,
                                     (AS3 unsigned int*)l, 16, 0, 0);
}

#define SBAR()  do { __builtin_amdgcn_s_barrier(); __builtin_amdgcn_sched_barrier(0); } while (0)
#define WAITV(n) do { asm volatile("s_waitcnt vmcnt(" #n ")" ::: "memory"); __builtin_amdgcn_sched_barrier(0); } while (0)
#define WAITL() do { asm volatile("s_waitcnt lgkmcnt(0)" ::: "memory"); __builtin_amdgcn_sched_barrier(0); } while (0)

// XCD-aware bijective tile swizzle (fallback path).
__device__ inline void xcd_swz(int nwg, int gx, int& bx, int& by) {
    const int flat = by * gx + bx;
    const int s = (flat & 7) * (nwg >> 3) + (flat >> 3);
    bx = s % gx;
    by = s / gx;
}

// ---- device-wide barrier: arrive (atomic add) + spin (atomic load) ----
// Monotonic counter, target = phase * gridDim. Release: threadfence before
// arrive (flushes this XCD's L2). Acquire: threadfence after sync (invalidate).
__device__ inline void gbar(unsigned* bar, unsigned target) {
    __syncthreads();                       // all waves drain own vmem (vmcnt0) + block sync
    if (threadIdx.x == 0) {
        __threadfence();                   // release to device scope
        atomicAdd(bar, 1u);
        while (__hip_atomic_load(bar, __ATOMIC_RELAXED, __HIP_MEMORY_SCOPE_AGENT) < target)
            __builtin_amdgcn_s_sleep(32);
    }
    __syncthreads();
    __threadfence();                       // acquire: invalidate stale caches
}

// ================= deep (BMQ*128)x256 f16 GEMM (R14, verified) =============
template<int OUT_MODE, int BMQ>
__device__ __forceinline__ void gemm_deep_body(
    char* __restrict__ smraw,
    const f16* __restrict__ A, const f16* __restrict__ B,
    float* __restrict__ Cf, f16* __restrict__ Ch,
    int K, int lda, int ldb, int ldc,
    long long sA, long long sB, long long sC,
    int bx, int by, int bz)
{
    constexpr int ACH   = BMQ * 8192;
    constexpr int BOFF  = 2 * ACH;
    constexpr int BUFSZ = 2 * ACH + 32768;
    constexpr int nI    = 4 * BMQ;

    A += (long long)bz * sA;
    B += (long long)bz * sB;

    const int tid  = threadIdx.x;
    const int lane = tid & 63;
    const int wave = tid >> 6;
    const int quad = lane >> 4;
    const int l16  = lane & 15;
    const int wm   = wave >> 2;
    const int wn   = wave & 3;

    const long long rowA0 = (long long)by * (BMQ * 128);
    const long long colB0 = (long long)bx * 256;

    const int line0 = tid >> 3;
    const int slog  = (tid & 7) ^ (line0 & 7);
    const int r0s   = line0 * 2 + (slog >> 2);
    const int c0s   = (slog & 3) * 8;

    const f16* aSrc0 = A + (rowA0 + r0s) * lda + c0s;
    const f16* aSrc1 = A + (rowA0 + 128 + r0s) * lda + c0s;
    const f16* bSrc0 = B + (colB0 + r0s) * ldb + c0s;
    const f16* bSrc1 = B + (colB0 + 128 + r0s) * ldb + c0s;

    const int nt = K >> 6;

    auto stageA = [&](int t, int kh) {
        char* dst = smraw + (t & 1) * BUFSZ + kh * ACH;
        const int k0 = t * 64 + kh * 32;
        async_load16(aSrc0 + k0, dst + tid * 16);
        if constexpr (BMQ == 2) async_load16(aSrc1 + k0, dst + 8192 + tid * 16);
    };
    auto stageB = [&](int t, int kh) {
        char* dst = smraw + (t & 1) * BUFSZ + BOFF + kh * 16384;
        const int k0 = t * 64 + kh * 32;
        async_load16(bSrc0 + k0, dst + tid * 16);
        async_load16(bSrc1 + k0, dst + 8192 + tid * 16);
    };

    const int h    = l16 >> 1;
    const int lofs = h * 128 + ((((l16 & 1) * 4 + quad) ^ h) << 4);
    const int aoff = wm * (ACH / 2) + lofs;
    const int boff = BOFF + wn * 4096 + lofs;

    f32x4 acc[nI][4];
#pragma unroll
    for (int i = 0; i < nI; i++)
#pragma unroll
        for (int j = 0; j < 4; j++) acc[i][j] = (f32x4){0.f, 0.f, 0.f, 0.f};

    stageA(0, 0); stageA(0, 1); stageB(0, 0); stageB(0, 1);
    WAITV(2);
    SBAR();

    for (int t = 0; t < nt; t++) {
        const char* buf = smraw + (t & 1) * BUFSZ;
        f16x8 av[nI], bv[2];

#pragma unroll
        for (int i = 0; i < nI; i++) av[i] = *(const f16x8*)(buf + aoff + i * 1024);
        bv[0] = *(const f16x8*)(buf + boff);
        bv[1] = *(const f16x8*)(buf + boff + 1024);
        if (t + 1 < nt) { stageA(t + 1, 0); stageA(t + 1, 1); }
        SBAR();
        WAITL();
        __builtin_amdgcn_s_setprio(1);
#pragma unroll
        for (int i = 0; i < nI; i++) {
            acc[i][0] = mfma16(av[i], bv[0], acc[i][0]);
            acc[i][1] = mfma16(av[i], bv[1], acc[i][1]);
        }
        __builtin_amdgcn_s_setprio(0);
        SBAR();

        bv[0] = *(const f16x8*)(buf + boff + 2048);
        bv[1] = *(const f16x8*)(buf + boff + 3072);
        if (t + 1 < nt) { stageB(t + 1, 0); stageB(t + 1, 1); }
        SBAR();
        WAITL();
        __builtin_amdgcn_s_setprio(1);
#pragma unroll
        for (int i = 0; i < nI; i++) {
            acc[i][2] = mfma16(av[i], bv[0], acc[i][2]);
            acc[i][3] = mfma16(av[i], bv[1], acc[i][3]);
        }
        __builtin_amdgcn_s_setprio(0);
        if (t + 1 < nt) { if constexpr (BMQ == 2) WAITV(8); else WAITV(6); }
        else { WAITV(0); }
        SBAR();

#pragma unroll
        for (int i = 0; i < nI; i++) av[i] = *(const f16x8*)(buf + ACH + aoff + i * 1024);
        bv[0] = *(const f16x8*)(buf + 16384 + boff);
        bv[1] = *(const f16x8*)(buf + 16384 + boff + 1024);
        SBAR();
        WAITL();
        __builtin_amdgcn_s_setprio(1);
#pragma unroll
        for (int i = 0; i < nI; i++) {
            acc[i][0] = mfma16(av[i], bv[0], acc[i][0]);
            acc[i][1] = mfma16(av[i], bv[1], acc[i][1]);
        }
        __builtin_amdgcn_s_setprio(0);
        SBAR();

        bv[0] = *(const f16x8*)(buf + 16384 + boff + 2048);
        bv[1] = *(const f16x8*)(buf + 16384 + boff + 3072);
        SBAR();
        WAITL();
        __builtin_amdgcn_s_setprio(1);
#pragma unroll
        for (int i = 0; i < nI; i++) {
            acc[i][2] = mfma16(av[i], bv[0], acc[i][2]);
            acc[i][3] = mfma16(av[i], bv[1], acc[i][3]);
        }
        __builtin_amdgcn_s_setprio(0);
        if (t + 1 < nt) { WAITV(2); } else { WAITV(0); }
        SBAR();
    }

    if constexpr (OUT_MODE == 2) {
        auto tr = (f16(*)[72])smraw;
        const int batch = (int)(rowA0 >> 11);
        const long long rib = rowA0 & 2047;
        const int c  = tid >> 1;
        const int r0 = (tid & 1) << 5;
#pragma unroll
        for (int h2 = 0; h2 < 2; h2++)
#pragma unroll
            for (int iq = 0; iq < 2; iq++) {
                __syncthreads();
                if (wm == h2) {
#pragma unroll
                    for (int i2 = 0; i2 < 4; i2++)
#pragma unroll
                        for (int j = 0; j < 4; j++)
#pragma unroll
                            for (int e = 0; e < 4; e++)
                                tr[wn * 64 + j * 16 + l16][i2 * 16 + quad * 4 + e] =
                                    (f16)acc[iq * 4 + i2][j][e];
                }
                __syncthreads();
                f16* vt = Ch + (long long)batch * 1024 * 2048 +
                          (long long)(colB0 + c) * ldc + rib + h2 * 128 + iq * 64 + r0;
#pragma unroll
                for (int u = 0; u < 32; u += 8)
                    *(f16x8*)(vt + u) = *(const f16x8*)&tr[c][r0 + u];
            }
        return;
    }

    const long long cOff = (long long)bz * sC +
                           (rowA0 + wm * (BMQ * 64) + quad * 4) * (long long)ldc +
                           colB0 + wn * 64 + l16;
#pragma unroll
    for (int i = 0; i < nI; i++)
#pragma unroll
        for (int e = 0; e < 4; e++) {
            const long long ro = cOff + (long long)(i * 16 + e) * ldc;
            if (OUT_MODE == 0) {
                float* rp = Cf + ro;
#pragma unroll
                for (int j = 0; j < 4; j++) rp[j * 16] = acc[i][j][e];
            } else {
                f16* rp = Ch + ro;
#pragma unroll
                for (int j = 0; j < 4; j++) rp[j * 16] = (f16)acc[i][j][e];
            }
        }
}

// ============== 128^2 split-bf16 body (Mt) — tid passed explicitly =========
template<typename E, bool SPLIT, int OUT_MODE, int BK>
__device__ __forceinline__ void gemm_body(
    char* __restrict__ smraw,
    const E* __restrict__ Ahi, const E* __restrict__ Alo,
    const E* __restrict__ Bhi, const E* __restrict__ Blo,
    float* __restrict__ Cf, f16* __restrict__ Ch,
    int K, int lda, int ldb, int ldc,
    long long sA, long long sB, long long sC,
    int bx, int by, int bz, int tid)
{
    using vec8 = typename vec8_of<E>::type;
    constexpr int TILE_BYTES = 128 * BK * (int)sizeof(E);
    constexpr int CPW = (TILE_BYTES / 1024) / 4;
    constexpr int SPR = (BK * (int)sizeof(E)) / 16;

    Ahi += (long long)bz * sA;
    Bhi += (long long)bz * sB;
    if (SPLIT) { Alo += (long long)bz * sA; Blo += (long long)bz * sB; }

    const int lane = tid & 63;
    const int wave = tid >> 6;
    const int quad = lane >> 4;
    const int l16  = lane & 15;
    const int wm   = (wave >> 1) * 64;
    const int wn   = (wave & 1) * 64;

    const long long rowA0 = (long long)by * 128;
    const long long colB0 = (long long)bx * 128;

    auto swz = [](int r) -> int { return (SPR == 8) ? (r & 7) : ((r >> 1) & 3); };

    int ofs[CPW], rr[CPW], cc8[CPW];
#pragma unroll
    for (int u = 0; u < CPW; u++) {
        ofs[u] = (wave * CPW + u) * 1024 + lane * 16;
        const int s = ofs[u] >> 4;
        rr[u]  = s / SPR;
        cc8[u] = (s & (SPR - 1)) ^ swz(rr[u]);
    }

    f32x4 acc[4][4];
#pragma unroll
    for (int i = 0; i < 4; i++)
#pragma unroll
        for (int j = 0; j < 4; j++) acc[i][j] = (f32x4){0.f, 0.f, 0.f, 0.f};

    for (int k0 = 0; k0 < K; k0 += BK) {
#pragma unroll
        for (int u = 0; u < CPW; u++) {
            async_load16(Ahi + (rowA0 + rr[u]) * lda + k0 + cc8[u] * 8, smraw + 0 * TILE_BYTES + ofs[u]);
            async_load16(Bhi + (colB0 + rr[u]) * ldb + k0 + cc8[u] * 8, smraw + 1 * TILE_BYTES + ofs[u]);
            if (SPLIT) {
                async_load16(Alo + (rowA0 + rr[u]) * lda + k0 + cc8[u] * 8, smraw + 2 * TILE_BYTES + ofs[u]);
                async_load16(Blo + (colB0 + rr[u]) * ldb + k0 + cc8[u] * 8, smraw + 3 * TILE_BYTES + ofs[u]);
            }
        }
        __syncthreads();

#pragma unroll
        for (int kh = 0; kh < BK / 32; kh++) {
            const int kc8 = kh * 4 + quad;
            vec8 a_hi[4], b_hi[4], a_lo[4], b_lo[4];
#pragma unroll
            for (int i = 0; i < 4; i++) {
                const int ra = wm + i * 16 + l16;
                const int rb = wn + i * 16 + l16;
                const int oa = ra * (SPR * 16) + ((kc8 ^ swz(ra)) << 4);
                const int ob = rb * (SPR * 16) + ((kc8 ^ swz(rb)) << 4);
                a_hi[i] = *(const vec8*)(smraw + 0 * TILE_BYTES + oa);
                b_hi[i] = *(const vec8*)(smraw + 1 * TILE_BYTES + ob);
                if (SPLIT) {
                    a_lo[i] = *(const vec8*)(smraw + 2 * TILE_BYTES + oa);
                    b_lo[i] = *(const vec8*)(smraw + 3 * TILE_BYTES + ob);
                }
            }
#pragma unroll
            for (int i = 0; i < 4; i++)
#pragma unroll
                for (int j = 0; j < 4; j++) {
                    acc[i][j] = mfma16(a_hi[i], b_hi[j], acc[i][j]);
                    if (SPLIT) {
                        acc[i][j] = mfma16(a_hi[i], b_lo[j], acc[i][j]);
                        acc[i][j] = mfma16(a_lo[i], b_hi[j], acc[i][j]);
                    }
                }
        }
        __syncthreads();
    }

    const long long cOff = (long long)bz * sC +
                           (rowA0 + wm + quad * 4) * (long long)ldc + colB0 + wn + l16;
#pragma unroll
    for (int i = 0; i < 4; i++)
#pragma unroll
        for (int e = 0; e < 4; e++) {
            const long long ro = cOff + (i * 16 + e) * ldc;
            if (OUT_MODE == 0) {
                float* rp = Cf + ro;
#pragma unroll
                for (int j = 0; j < 4; j++) rp[j * 16] = acc[i][j][e];
            } else {
                f16* rp = Ch + ro;
#pragma unroll
                for (int j = 0; j < 4; j++) rp[j * 16] = (f16)acc[i][j][e];
            }
        }
}

// ---- 512-thread softmax of one 2048-wide fp32 row -> f16 ----
__device__ __forceinline__ void softmax512(const float* __restrict__ S,
                                           f16* __restrict__ P,
                                           long long row, int tid, char* smraw)
{
    float* red = (float*)smraw;            // 8 floats
    const float4* p = (const float4*)(S + row * 2048);
    f16* q = P + row * 2048;
    const int wv = tid >> 6, lane = tid & 63;

    float4 va = p[tid];
    float m = fmaxf(fmaxf(va.x, va.y), fmaxf(va.z, va.w));
#pragma unroll
    for (int off = 32; off > 0; off >>= 1) m = fmaxf(m, __shfl_xor(m, off, 64));
    __syncthreads();                       // protect red from previous row
    if (lane == 0) red[wv] = m;
    __syncthreads();
    m = fmaxf(fmaxf(fmaxf(red[0], red[1]), fmaxf(red[2], red[3])),
              fmaxf(fmaxf(red[4], red[5]), fmaxf(red[6], red[7])));

    float e0 = __expf(va.x - m), e1 = __expf(va.y - m);
    float e2 = __expf(va.z - m), e3 = __expf(va.w - m);
    float s = (e0 + e1) + (e2 + e3);
#pragma unroll
    for (int off = 32; off > 0; off >>= 1) s += __shfl_xor(s, off, 64);
    __syncthreads();
    if (lane == 0) red[wv] = s;
    __syncthreads();
    s = ((red[0] + red[1]) + (red[2] + red[3])) +
        ((red[4] + red[5]) + (red[6] + red[7]));

    const float inv = 1.0f / s;
    f16x4 o = {(f16)(e0 * inv), (f16)(e1 * inv), (f16)(e2 * inv), (f16)(e3 * inv)};
    *(f16x4*)(q + tid * 4) = o;
}

// ================= persistent mega-kernel =================
__global__ __launch_bounds__(512, 2) void mega(
    const float* __restrict__ X, const float* __restrict__ Wq,
    const float* __restrict__ Wk, const float* __restrict__ Wv,
    float* __restrict__ out, f16* __restrict__ Xf,
    bf16* __restrict__ Wq_h, bf16* __restrict__ Wq_l,
    bf16* __restrict__ Wk_h, bf16* __restrict__ Wk_l,
    f16* __restrict__ Wvt_f, f16* __restrict__ Mt_f,
    f16* __restrict__ T, f16* __restrict__ Vt,
    float* __restrict__ Sc, f16* __restrict__ P, unsigned* bar)
{
    extern __shared__ char smraw[];
    const int b = blockIdx.x, tid = threadIdx.x;

    // ---- S1: W split (1024 units) + Wv transpose (512 pair-units) ----
    for (int u = b; u < 1536; u += 256) {
        if (u < 1024) {
            const float4* W = (const float4*)(u < 512 ? Wq : Wk);
            bf16* hh = u < 512 ? Wq_h : Wk_h;
            bf16* ll = u < 512 ? Wq_l : Wk_l;
            long long i = (long long)(u & 511) * 512 + tid;
            float4 v = W[i];
            bf16 a0 = (bf16)v.x, a1 = (bf16)v.y, a2 = (bf16)v.z, a3 = (bf16)v.w;
            bf16x4 hv = {a0, a1, a2, a3};
            bf16x4 lv = {(bf16)(v.x - (float)a0), (bf16)(v.y - (float)a1),
                         (bf16)(v.z - (float)a2), (bf16)(v.w - (float)a3)};
            *(bf16x4*)(hh + 4 * i) = hv;
            *(bf16x4*)(ll + 4 * i) = lv;
        } else {
            auto t = (float(*)[32][33])smraw;      // 2 tiles, 8448 B
            const int tile = (u - 1024) * 2 + (tid >> 8);
            const int sub = tid & 255;
            const int bx = (tile & 31) * 32, by = (tile >> 5) * 32;
            const int tx = sub & 31, ty = sub >> 5;
            __syncthreads();                       // LDS reuse across iters
#pragma unroll
            for (int i = 0; i < 32; i += 8)
                t[tid >> 8][ty + i][tx] = Wv[(long long)(by + ty + i) * 1024 + bx + tx];
            __syncthreads();
#pragma unroll
            for (int i = 0; i < 32; i += 8) {
                long long o = (long long)(bx + ty + i) * 1024 + by + tx;
                Wvt_f[o] = (f16)t[tid >> 8][tx][ty + i];
            }
        }
    }
    gbar(bar, 256);

    // ---- S2: Mt (blocks 0..63, duplicated half-blocks) || X->f16 (64..255) --
    if (b < 64) {
        gemm_body<bf16, true, 1, 32>(smraw, Wk_h, Wk_l, Wq_h, Wq_l,
                                     nullptr, Mt_f, 1024, 1024, 1024, 1024,
                                     0, 0, 0, b & 7, b >> 3, 0, tid & 255);
    } else {
        for (int u = b - 64; u < 4096; u += 192) {
            long long i = (long long)u * 512 + tid;
            float4 v = ((const float4*)X)[i];
            f16x4 fv = {(f16)v.x, (f16)v.y, (f16)v.z, (f16)v.w};
            *(f16x4*)(Xf + 4 * i) = fv;
        }
    }
    gbar(bar, 512);

    // ---- S3: T (b<128) || Vt (b>=128), XCD-local by-grouping ----
    if (b < 128) {
        const int by = (b & 7) * 4 + ((b >> 3) & 3), bx = b >> 5;
        gemm_deep_body<1, 2>(smraw, Xf, Mt_f, nullptr, T, 1024, 1024, 1024, 1024,
                             0, 0, 0, bx, by, 0);
    } else {
        const int b2 = b - 128;
        const int by = (b2 & 7) * 4 + ((b2 >> 3) & 3), bx = b2 >> 5;
        gemm_deep_body<2, 2>(smraw, Xf, Wvt_f, nullptr, Vt, 1024, 1024, 1024, 2048,
                             0, 0, 0, bx, by, 0);
    }
    gbar(bar, 768);

    // ---- S4: Sc = T . Xf^T per batch ----
    {
        const int rem = b & 63, bz = b >> 6;
        const int by = rem & 7, bx = rem >> 3;
        gemm_deep_body<0, 2>(smraw, T, Xf, Sc, nullptr, 1024, 1024, 1024, 2048,
                             2048LL * 1024, 2048LL * 1024, 2048LL * 2048, bx, by, bz);
    }
    gbar(bar, 1024);

    // ---- S5: softmax, 32 rows/block ----
    for (int r = 0; r < 32; r++)
        softmax512(Sc, P, (long long)b * 32 + r, tid, smraw);
    gbar(bar, 1280);

    // ---- S6: out = P . Vt^T ----
    {
        const int rem = b & 63, bz = b >> 6;
        const int by = (rem & 7) * 2 + ((rem >> 3) & 1), bx = rem >> 4;
        gemm_deep_body<0, 1>(smraw, P, Vt, out, nullptr, 2048, 2048, 2048, 1024,
                             2048LL * 2048, 1024LL * 2048, 2048LL * 1024, bx, by, bz);
    }
}

// =================== fallback kernels (R14, verified 275us) ================
__global__ __launch_bounds__(512, 2) void tv8d(
    const f16* __restrict__ Xf, const f16* __restrict__ Mt_f,
    const f16* __restrict__ Wvt_f, f16* __restrict__ T, f16* __restrict__ Vt)
{
    extern __shared__ char smraw[];
    int bx = blockIdx.x, by = blockIdx.y;
    xcd_swz(256, 8, bx, by);
    if (bx < 4)
        gemm_deep_body<1, 2>(smraw, Xf, Mt_f, nullptr, T, 1024, 1024, 1024, 1024,
                             0, 0, 0, bx, by, 0);
    else
        gemm_deep_body<2, 2>(smraw, Xf, Wvt_f, nullptr, Vt, 1024, 1024, 1024, 2048,
                             0, 0, 0, bx - 4, by, 0);
}

template<int OUT_MODE, int BMQ>
__global__ __launch_bounds__(512, 2) void gemmd_k(
    const f16* __restrict__ A, const f16* __restrict__ B,
    float* __restrict__ Cf, f16* __restrict__ Ch,
    int K, int lda, int ldb, int ldc,
    long long sA, long long sB, long long sC)
{
    extern __shared__ char smraw[];
    int bx = blockIdx.x, by = blockIdx.y;
    xcd_swz(gridDim.x * gridDim.y, gridDim.x, bx, by);
    gemm_deep_body<OUT_MODE, BMQ>(smraw, A, B, Cf, Ch, K, lda, ldb, ldc,
                                  sA, sB, sC, bx, by, blockIdx.z);
}

template<typename E, bool SPLIT, int OUT_MODE, int BK>
__global__ __launch_bounds__(256) void gemm_bt(
    const E* __restrict__ Ahi, const E* __restrict__ Alo,
    const E* __restrict__ Bhi, const E* __restrict__ Blo,
    float* __restrict__ Cf, f16* __restrict__ Ch,
    int K, int lda, int ldb, int ldc,
    long long sA, long long sB, long long sC)
{
    extern __shared__ char smraw[];
    gemm_body<E, SPLIT, OUT_MODE, BK>(smraw, Ahi, Alo, Bhi, Blo, Cf, Ch,
                                      K, lda, ldb, ldc, sA, sB, sC,
                                      blockIdx.x, blockIdx.y, blockIdx.z,
                                      threadIdx.x);
}

__global__ __launch_bounds__(256) void prep_all(
    const float4* __restrict__ X, f16* __restrict__ Xf,
    const float* __restrict__ Wq, const float* __restrict__ Wk, const float* __restrict__ Wv,
    bf16* __restrict__ Wq_h, bf16* __restrict__ Wq_l,
    bf16* __restrict__ Wk_h, bf16* __restrict__ Wk_l,
    f16* __restrict__ Wvt_f)
{
    int b = blockIdx.x;
    if (b < 8192) {
        long long i = (long long)b * 256 + threadIdx.x;
        float4 v = X[i];
        f16x4 fv = {(f16)v.x, (f16)v.y, (f16)v.z, (f16)v.w};
        *(f16x4*)(Xf + 4 * i) = fv;
    } else if (b < 10240) {
        const int b2 = b - 8192;
        const float4* W = (const float4*)(b2 < 1024 ? Wq : Wk);
        bf16* hh = b2 < 1024 ? Wq_h : Wk_h;
        bf16* ll = b2 < 1024 ? Wq_l : Wk_l;
        long long i = (long long)(b2 & 1023) * 256 + threadIdx.x;
        float4 v = W[i];
        bf16 a0 = (bf16)v.x, a1 = (bf16)v.y, a2 = (bf16)v.z, a3 = (bf16)v.w;
        bf16x4 hv = {a0, a1, a2, a3};
        bf16x4 lv = {(bf16)(v.x - (float)a0), (bf16)(v.y - (float)a1),
                     (bf16)(v.z - (float)a2), (bf16)(v.w - (float)a3)};
        *(bf16x4*)(hh + 4 * i) = hv;
        *(bf16x4*)(ll + 4 * i) = lv;
    } else {
        const int b3 = b - 10240;
        __shared__ float t[32][33];
        const int bx = (b3 & 31) * 32, by = (b3 >> 5) * 32;
        const int tx = threadIdx.x & 31, ty = threadIdx.x >> 5;
#pragma unroll
        for (int i = 0; i < 32; i += 8)
            t[ty + i][tx] = Wv[(long long)(by + ty + i) * 1024 + bx + tx];
        __syncthreads();
#pragma unroll
        for (int i = 0; i < 32; i += 8) {
            long long o = (long long)(bx + ty + i) * 1024 + by + tx;
            Wvt_f[o] = (f16)t[tx][ty + i];
        }
    }
}

__global__ __launch_bounds__(256) void softmax_f16(const float* __restrict__ S,
                                                   f16* __restrict__ P, int n)
{
    const long long row = blockIdx.x;
    const float4* p = (const float4*)(S + row * (long long)n);
    f16* q = P + row * (long long)n;
    const int tid = threadIdx.x;
    const int wv = tid >> 6, lane = tid & 63;

    float4 va = p[tid], vb = p[tid + 256];
    float v[8] = {va.x, va.y, va.z, va.w, vb.x, vb.y, vb.z, vb.w};
    float m = -3.4e38f;
#pragma unroll
    for (int i = 0; i < 8; i++) m = fmaxf(m, v[i]);
#pragma unroll
    for (int off = 32; off > 0; off >>= 1) m = fmaxf(m, __shfl_xor(m, off, 64));

    __shared__ float red[4];
    if (lane == 0) red[wv] = m;
    __syncthreads();
    m = fmaxf(fmaxf(red[0], red[1]), fmaxf(red[2], red[3]));

    float s = 0.f;
#pragma unroll
    for (int i = 0; i < 8; i++) { v[i] = __expf(v[i] - m); s += v[i]; }
#pragma unroll
    for (int off = 32; off > 0; off >>= 1) s += __shfl_xor(s, off, 64);
    __syncthreads();
    if (lane == 0) red[wv] = s;
    __syncthreads();
    s = red[0] + red[1] + red[2] + red[3];

    const float inv = 1.0f / s;
    f16x4 o0 = {(f16)(v[0] * inv), (f16)(v[1] * inv), (f16)(v[2] * inv), (f16)(v[3] * inv)};
    f16x4 o1 = {(f16)(v[4] * inv), (f16)(v[5] * inv), (f16)(v[6] * inv), (f16)(v[7] * inv)};
    *(f16x4*)(q + tid * 4) = o0;
    *(f16x4*)(q + 1024 + tid * 4) = o1;
}

extern "C" void kernel_launch(void* const* d_in, const int* in_sizes, int n_in,
                              void* d_out, int out_size, void* d_ws, size_t ws_size,
                              hipStream_t stream) {
    const float* X  = (const float*)d_in[0];   // [8192,1024]
    const float* Wq = (const float*)d_in[1];   // [1024,1024]
    const float* Wk = (const float*)d_in[2];
    const float* Wv = (const float*)d_in[3];
    float* out = (float*)d_out;                // [8192,1024]

    char* w = (char*)d_ws;
    const long long MB = 1024LL * 1024;
    f16*  Xf    = (f16*) (w + 0 * MB);     // 16 MB
    bf16* Wq_h  = (bf16*)(w + 16 * MB);    // 2 MB
    bf16* Wq_l  = (bf16*)(w + 18 * MB);
    bf16* Wk_h  = (bf16*)(w + 20 * MB);
    bf16* Wk_l  = (bf16*)(w + 22 * MB);
    f16*  Wvt_f = (f16*) (w + 24 * MB);    // 2 MB (transposed)
    f16*  Mt_f  = (f16*) (w + 26 * MB);    // 2 MB
    f16*  T     = (f16*) (w + 28 * MB);    // 16 MB [8192,1024]
    f16*  Vt    = (f16*) (w + 44 * MB);    // 16 MB [4][1024][2048]
    float* Sc   = (float*)(w + 60 * MB);   // 64 MB
    f16*  P     = (f16*) (w + 124 * MB);   // 32 MB -> ends 156 MB

    static int attrs_ok = -1;
    if (attrs_ok < 0) {
        auto* pSc = gemmd_k<0, 2>;
        auto* pPv = gemmd_k<0, 1>;
        hipError_t e0 = hipFuncSetAttribute(
            reinterpret_cast<const void*>(mega),
            hipFuncAttributeMaxDynamicSharedMemorySize, 131072);
        hipError_t e1 = hipFuncSetAttribute(
            reinterpret_cast<const void*>(tv8d),
            hipFuncAttributeMaxDynamicSharedMemorySize, 131072);
        hipError_t e2 = hipFuncSetAttribute(
            reinterpret_cast<const void*>(pSc),
            hipFuncAttributeMaxDynamicSharedMemorySize, 131072);
        hipError_t e3 = hipFuncSetAttribute(
            reinterpret_cast<const void*>(pPv),
            hipFuncAttributeMaxDynamicSharedMemorySize, 98304);
        attrs_ok = ((e1 == hipSuccess && e2 == hipSuccess && e3 == hipSuccess) ? 1 : 0)
                 | ((e0 == hipSuccess) ? 2 : 0);
    }

    // ---- try the persistent mega-kernel ----
    if ((attrs_ok & 2) && ws_size >= (size_t)(156 * MB + 64)) {
        unsigned* bar = (unsigned*)(w + 156 * MB);
        hipMemsetAsync(bar, 0, 4, stream);
        void* kargs[] = { (void*)&X, (void*)&Wq, (void*)&Wk, (void*)&Wv,
                          (void*)&out, (void*)&Xf,
                          (void*)&Wq_h, (void*)&Wq_l, (void*)&Wk_h, (void*)&Wk_l,
                          (void*)&Wvt_f, (void*)&Mt_f, (void*)&T, (void*)&Vt,
                          (void*)&Sc, (void*)&P, (void*)&bar };
        hipError_t err = hipLaunchCooperativeKernel(
            reinterpret_cast<void*>(mega), dim3(256), dim3(512), kargs,
            131072, stream);
        if (err == hipSuccess) return;
    }

    // ---- fallback: R14 6-dispatch path ----
    dim3 blk(256);
    prep_all<<<dim3(11264), blk, 0, stream>>>(
        (const float4*)X, Xf, Wq, Wk, Wv, Wq_h, Wq_l, Wk_h, Wk_l, Wvt_f);
    gemm_bt<bf16, true, 1, 32><<<dim3(8, 8, 1), blk, 32768, stream>>>(
        Wk_h, Wk_l, Wq_h, Wq_l, nullptr, Mt_f,
        1024, 1024, 1024, 1024, 0, 0, 0);
    if (attrs_ok & 1) {
        tv8d<<<dim3(8, 32), dim3(512), 131072, stream>>>(Xf, Mt_f, Wvt_f, T, Vt);
        gemmd_k<0, 2><<<dim3(8, 8, 4), dim3(512), 131072, stream>>>(
            T, Xf, Sc, nullptr, 1024, 1024, 1024, 2048,
            2048LL * 1024, 2048LL * 1024, 2048LL * 2048);
        softmax_f16<<<dim3(4 * 2048), blk, 0, stream>>>(Sc, P, 2048);
        gemmd_k<0, 1><<<dim3(4, 16, 4), dim3(512), 98304, stream>>>(
            P, Vt, out, nullptr, 2048, 2048, 2048, 1024,
            2048LL * 2048, 1024LL * 2048, 2048LL * 1024);
    }
}

// Round 8
// 310.360 us; speedup vs baseline: 1.8393x; 1.8393x over previous
//
#include <hip/hip_runtime.h>
#include <math.h>

// Round 16: fusion permanently abandoned (2 failures, distinct causes).
// A/B round: Sc + PV move to "light" m97-style GEMM — 128^2 tile, BK=32,
// SINGLE 16KB LDS buffer, plain __syncthreads, 256 thr, XCD swizzle, high
// occupancy (3-6 blocks/CU). Theory: deep kernels are LDS-issue-bound at
// 1 block/CU (24KB LDS read /tile/wave at ~85B/cyc single-wave rate = 2300cyc
// vs 620cyc MFMA -> 27% MfmaUtil, matches measurement); m97 fixes via TLP.
// tv8d stays deep as the in-profile comparator.
//   D1 prep_all : X->f16 || Wq,Wk bf16-split || Wv transpose->f16
//   D2 mt       : Mt = Wk_s Wq_s^T (split-bf16 3-MFMA, 128^2) -> f16
//   D3 tv8d     : T || Vt (deep 256^2, 128KB)   [comparator]
//   D4 sc_lt    : Sc = T . Xf^T -> fp32         [light 128^2]
//   D5 softmax  : P = softmax(Sc) -> f16
//   D6 pv_lt    : out = P . Vt^T                [light 128^2]

typedef __bf16 bf16;
typedef _Float16 f16;
typedef __bf16 bf16x8 __attribute__((ext_vector_type(8)));
typedef __bf16 bf16x4 __attribute__((ext_vector_type(4)));
typedef _Float16 f16x4 __attribute__((ext_vector_type(4)));
typedef _Float16 f16x8 __attribute__((ext_vector_type(8)));
typedef float  f32x4  __attribute__((ext_vector_type(4)));

template<typename E> struct vec8_of;
template<> struct vec8_of<bf16> { using type = bf16x8; };
template<> struct vec8_of<f16>  { using type = f16x8; };

__device__ inline f32x4 mfma16(bf16x8 a, bf16x8 b, f32x4 c) {
    return __builtin_amdgcn_mfma_f32_16x16x32_bf16(a, b, c, 0, 0, 0);
}
__device__ inline f32x4 mfma16(f16x8 a, f16x8 b, f32x4 c) {
    return __builtin_amdgcn_mfma_f32_16x16x32_f16(a, b, c, 0, 0, 0);
}

#define AS1 __attribute__((address_space(1)))
#define AS3 __attribute__((address_space(3)))

template<typename E>
__device__ inline void async_load16(const E* g, void* l) {
    __builtin_amdgcn_global_load_lds((const AS1 unsigned int*)g,
                                     (AS3 unsigned int*)l, 16, 0, 0);
}

#define SBAR()  do { __builtin_amdgcn_s_barrier(); __builtin_amdgcn_sched_barrier(0); } while (0)
#define WAITV(n) do { asm volatile("s_waitcnt vmcnt(" #n ")" ::: "memory"); __builtin_amdgcn_sched_barrier(0); } while (0)
#define WAITL() do { asm volatile("s_waitcnt lgkmcnt(0)" ::: "memory"); __builtin_amdgcn_sched_barrier(0); } while (0)

// XCD-aware bijective tile swizzle (nwg % 8 == 0).
__device__ inline void xcd_swz(int nwg, int gx, int& bx, int& by) {
    const int flat = by * gx + bx;
    const int s = (flat & 7) * (nwg >> 3) + (flat >> 3);
    bx = s % gx;
    by = s / gx;
}

// ============== light/base 128^2 GEMM body (R2-verified code path) =========
// C[M,N] = sum_k A[m,k]*B[n,k]  (B in [N,K] layout).
// SPLIT: bf16 hi/lo 3-MFMA (Mt). DBUF: double-buffer + counted vmcnt (tv
// fallback only). OUT_MODE: 0 fp32; 1 f16; 2 f16 transposed per-batch.
template<typename E, bool SPLIT, int OUT_MODE, int BK, bool DBUF>
__device__ __forceinline__ void gemm_body(
    char* __restrict__ smraw,
    const E* __restrict__ Ahi, const E* __restrict__ Alo,
    const E* __restrict__ Bhi, const E* __restrict__ Blo,
    float* __restrict__ Cf, f16* __restrict__ Ch,
    int K, int lda, int ldb, int ldc,
    long long sA, long long sB, long long sC,
    int bx, int by, int bz)
{
    using vec8 = typename vec8_of<E>::type;
    constexpr int TILE_BYTES = 128 * BK * (int)sizeof(E);   // 8192 @ BK=32
    constexpr int CPW = (TILE_BYTES / 1024) / 4;            // 1KB chunks per wave
    constexpr int SPR = (BK * (int)sizeof(E)) / 16;         // 16B slots per row
    constexpr int NMAT = SPLIT ? 4 : 2;

    Ahi += (long long)bz * sA;
    Bhi += (long long)bz * sB;
    if (SPLIT) { Alo += (long long)bz * sA; Blo += (long long)bz * sB; }

    const int tid  = threadIdx.x;
    const int lane = tid & 63;
    const int wave = tid >> 6;
    const int quad = lane >> 4;
    const int l16  = lane & 15;
    const int wm   = (wave >> 1) * 64;
    const int wn   = (wave & 1) * 64;

    const long long rowA0 = (long long)by * 128;
    const long long colB0 = (long long)bx * 128;

    auto swz = [](int r) -> int { return (SPR == 8) ? (r & 7) : ((r >> 1) & 3); };

    int ofs[CPW], rr[CPW], cc8[CPW];
#pragma unroll
    for (int u = 0; u < CPW; u++) {
        ofs[u] = (wave * CPW + u) * 1024 + lane * 16;
        const int s = ofs[u] >> 4;
        rr[u]  = s / SPR;
        cc8[u] = (s & (SPR - 1)) ^ swz(rr[u]);
    }

    f32x4 acc[4][4];
#pragma unroll
    for (int i = 0; i < 4; i++)
#pragma unroll
        for (int j = 0; j < 4; j++) acc[i][j] = (f32x4){0.f, 0.f, 0.f, 0.f};

    auto stage = [&](int k0, int buf) {
        char* base = smraw + buf * (NMAT * TILE_BYTES);
#pragma unroll
        for (int u = 0; u < CPW; u++) {
            async_load16(Ahi + (rowA0 + rr[u]) * lda + k0 + cc8[u] * 8, base + 0 * TILE_BYTES + ofs[u]);
            async_load16(Bhi + (colB0 + rr[u]) * ldb + k0 + cc8[u] * 8, base + 1 * TILE_BYTES + ofs[u]);
            if (SPLIT) {
                async_load16(Alo + (rowA0 + rr[u]) * lda + k0 + cc8[u] * 8, base + 2 * TILE_BYTES + ofs[u]);
                async_load16(Blo + (colB0 + rr[u]) * ldb + k0 + cc8[u] * 8, base + 3 * TILE_BYTES + ofs[u]);
            }
        }
    };

    auto compute = [&](int buf) {
        char* base = smraw + buf * (NMAT * TILE_BYTES);
#pragma unroll
        for (int kh = 0; kh < BK / 32; kh++) {
            const int kc8 = kh * 4 + quad;
            vec8 a_hi[4], b_hi[4], a_lo[4], b_lo[4];
#pragma unroll
            for (int i = 0; i < 4; i++) {
                const int ra = wm + i * 16 + l16;
                const int rb = wn + i * 16 + l16;
                const int oa = ra * (SPR * 16) + ((kc8 ^ swz(ra)) << 4);
                const int ob = rb * (SPR * 16) + ((kc8 ^ swz(rb)) << 4);
                a_hi[i] = *(const vec8*)(base + 0 * TILE_BYTES + oa);
                b_hi[i] = *(const vec8*)(base + 1 * TILE_BYTES + ob);
                if (SPLIT) {
                    a_lo[i] = *(const vec8*)(base + 2 * TILE_BYTES + oa);
                    b_lo[i] = *(const vec8*)(base + 3 * TILE_BYTES + ob);
                }
            }
#pragma unroll
            for (int i = 0; i < 4; i++)
#pragma unroll
                for (int j = 0; j < 4; j++) {
                    acc[i][j] = mfma16(a_hi[i], b_hi[j], acc[i][j]);
                    if (SPLIT) {
                        acc[i][j] = mfma16(a_hi[i], b_lo[j], acc[i][j]);
                        acc[i][j] = mfma16(a_lo[i], b_hi[j], acc[i][j]);
                    }
                }
        }
    };

    if (DBUF) {
        const int nt = K / BK;
        stage(0, 0);
        for (int t = 0; t < nt; t++) {
            const int cur = t & 1;
            if (t + 1 < nt) {
                stage((t + 1) * BK, cur ^ 1);
                asm volatile("s_waitcnt vmcnt(4)" ::: "memory");
            } else {
                asm volatile("s_waitcnt vmcnt(0)" ::: "memory");
            }
            __builtin_amdgcn_s_barrier();
            asm volatile("" ::: "memory");
            compute(cur);
            asm volatile("s_waitcnt lgkmcnt(0)" ::: "memory");
            __builtin_amdgcn_sched_barrier(0);
            __builtin_amdgcn_s_barrier();
            asm volatile("" ::: "memory");
        }
    } else {
        for (int k0 = 0; k0 < K; k0 += BK) {
            stage(k0, 0);
            __syncthreads();
            compute(0);
            __syncthreads();
        }
    }

    if (OUT_MODE == 2) {
        auto tr = (f16(*)[130])smraw;    // 128 x 130 f16 = 33280 B
#pragma unroll
        for (int i = 0; i < 4; i++)
#pragma unroll
            for (int j = 0; j < 4; j++)
#pragma unroll
                for (int e = 0; e < 4; e++)
                    tr[wn + j * 16 + l16][wm + i * 16 + quad * 4 + e] = (f16)acc[i][j][e];
        __syncthreads();
        const int batch = (int)(rowA0 >> 11);
        const int rib   = (int)(rowA0 & 2047);
        const int c  = tid >> 1;
        const int r0 = (tid & 1) << 6;
        f16* vt = Ch + (long long)batch * 1024 * 2048 + (long long)(colB0 + c) * ldc + rib + r0;
#pragma unroll
        for (int u = 0; u < 64; u += 8)
            *(f16x8*)(vt + u) = *(const f16x8*)&tr[c][r0 + u];
        return;
    }

    const long long cOff = (long long)bz * sC +
                           (rowA0 + wm + quad * 4) * (long long)ldc + colB0 + wn + l16;
#pragma unroll
    for (int i = 0; i < 4; i++)
#pragma unroll
        for (int e = 0; e < 4; e++) {
            const long long ro = cOff + (i * 16 + e) * ldc;
            if (OUT_MODE == 0) {
                float* rp = Cf + ro;
#pragma unroll
                for (int j = 0; j < 4; j++) rp[j * 16] = acc[i][j][e];
            } else {
                f16* rp = Ch + ro;
#pragma unroll
                for (int j = 0; j < 4; j++) rp[j * 16] = (f16)acc[i][j][e];
            }
        }
}

// ---- light wrapper: 128^2, BK=32, single 16KB buffer, XCD swizzle ----
template<int OUT_MODE>
__global__ __launch_bounds__(256) void gemm_lt(
    const f16* __restrict__ A, const f16* __restrict__ B,
    float* __restrict__ Cf, f16* __restrict__ Ch,
    int K, int lda, int ldb, int ldc,
    long long sA, long long sB, long long sC)
{
    extern __shared__ char smraw[];
    int bx = blockIdx.x, by = blockIdx.y;
    xcd_swz(gridDim.x * gridDim.y, gridDim.x, bx, by);
    gemm_body<f16, false, OUT_MODE, 32, false>(smraw, A, nullptr, B, nullptr,
                                               Cf, Ch, K, lda, ldb, ldc,
                                               sA, sB, sC, bx, by, blockIdx.z);
}

// ---- Mt wrapper (verified) ----
template<typename E, bool SPLIT, int OUT_MODE, int BK>
__global__ __launch_bounds__(256) void gemm_bt(
    const E* __restrict__ Ahi, const E* __restrict__ Alo,
    const E* __restrict__ Bhi, const E* __restrict__ Blo,
    float* __restrict__ Cf, f16* __restrict__ Ch,
    int K, int lda, int ldb, int ldc,
    long long sA, long long sB, long long sC)
{
    extern __shared__ char smraw[];
    gemm_body<E, SPLIT, OUT_MODE, BK, false>(smraw, Ahi, Alo, Bhi, Blo, Cf, Ch,
                                             K, lda, ldb, ldc, sA, sB, sC,
                                             blockIdx.x, blockIdx.y, blockIdx.z);
}

// ---- tv fallback (R2-verified DBUF light pair) ----
__global__ __launch_bounds__(256) void tv_gemm(
    const f16* __restrict__ Xf, const f16* __restrict__ Mt_f,
    const f16* __restrict__ Wvt_f,
    f16* __restrict__ T, f16* __restrict__ Vt)
{
    extern __shared__ char smraw[];
    if (blockIdx.x < 8)
        gemm_body<f16, false, 1, 32, true>(smraw, Xf, nullptr, Mt_f, nullptr,
                                           nullptr, T, 1024, 1024, 1024, 1024,
                                           0, 0, 0, blockIdx.x, blockIdx.y, 0);
    else
        gemm_body<f16, false, 2, 32, true>(smraw, Xf, nullptr, Wvt_f, nullptr,
                                           nullptr, Vt, 1024, 1024, 1024, 2048,
                                           0, 0, 0, blockIdx.x - 8, blockIdx.y, 0);
}

// ================= deep 256^2 GEMM (R14, verified) — tv comparator =========
template<int OUT_MODE, int BMQ>
__device__ __forceinline__ void gemm_deep_body(
    char* __restrict__ smraw,
    const f16* __restrict__ A, const f16* __restrict__ B,
    float* __restrict__ Cf, f16* __restrict__ Ch,
    int K, int lda, int ldb, int ldc,
    long long sA, long long sB, long long sC,
    int bx, int by, int bz)
{
    constexpr int ACH   = BMQ * 8192;
    constexpr int BOFF  = 2 * ACH;
    constexpr int BUFSZ = 2 * ACH + 32768;
    constexpr int nI    = 4 * BMQ;

    A += (long long)bz * sA;
    B += (long long)bz * sB;

    const int tid  = threadIdx.x;
    const int lane = tid & 63;
    const int wave = tid >> 6;
    const int quad = lane >> 4;
    const int l16  = lane & 15;
    const int wm   = wave >> 2;
    const int wn   = wave & 3;

    const long long rowA0 = (long long)by * (BMQ * 128);
    const long long colB0 = (long long)bx * 256;

    const int line0 = tid >> 3;
    const int slog  = (tid & 7) ^ (line0 & 7);
    const int r0s   = line0 * 2 + (slog >> 2);
    const int c0s   = (slog & 3) * 8;

    const f16* aSrc0 = A + (rowA0 + r0s) * lda + c0s;
    const f16* aSrc1 = A + (rowA0 + 128 + r0s) * lda + c0s;
    const f16* bSrc0 = B + (colB0 + r0s) * ldb + c0s;
    const f16* bSrc1 = B + (colB0 + 128 + r0s) * ldb + c0s;

    const int nt = K >> 6;

    auto stageA = [&](int t, int kh) {
        char* dst = smraw + (t & 1) * BUFSZ + kh * ACH;
        const int k0 = t * 64 + kh * 32;
        async_load16(aSrc0 + k0, dst + tid * 16);
        if constexpr (BMQ == 2) async_load16(aSrc1 + k0, dst + 8192 + tid * 16);
    };
    auto stageB = [&](int t, int kh) {
        char* dst = smraw + (t & 1) * BUFSZ + BOFF + kh * 16384;
        const int k0 = t * 64 + kh * 32;
        async_load16(bSrc0 + k0, dst + tid * 16);
        async_load16(bSrc1 + k0, dst + 8192 + tid * 16);
    };

    const int h    = l16 >> 1;
    const int lofs = h * 128 + ((((l16 & 1) * 4 + quad) ^ h) << 4);
    const int aoff = wm * (ACH / 2) + lofs;
    const int boff = BOFF + wn * 4096 + lofs;

    f32x4 acc[nI][4];
#pragma unroll
    for (int i = 0; i < nI; i++)
#pragma unroll
        for (int j = 0; j < 4; j++) acc[i][j] = (f32x4){0.f, 0.f, 0.f, 0.f};

    stageA(0, 0); stageA(0, 1); stageB(0, 0); stageB(0, 1);
    WAITV(2);
    SBAR();

    for (int t = 0; t < nt; t++) {
        const char* buf = smraw + (t & 1) * BUFSZ;
        f16x8 av[nI], bv[2];

#pragma unroll
        for (int i = 0; i < nI; i++) av[i] = *(const f16x8*)(buf + aoff + i * 1024);
        bv[0] = *(const f16x8*)(buf + boff);
        bv[1] = *(const f16x8*)(buf + boff + 1024);
        if (t + 1 < nt) { stageA(t + 1, 0); stageA(t + 1, 1); }
        SBAR();
        WAITL();
        __builtin_amdgcn_s_setprio(1);
#pragma unroll
        for (int i = 0; i < nI; i++) {
            acc[i][0] = mfma16(av[i], bv[0], acc[i][0]);
            acc[i][1] = mfma16(av[i], bv[1], acc[i][1]);
        }
        __builtin_amdgcn_s_setprio(0);
        SBAR();

        bv[0] = *(const f16x8*)(buf + boff + 2048);
        bv[1] = *(const f16x8*)(buf + boff + 3072);
        if (t + 1 < nt) { stageB(t + 1, 0); stageB(t + 1, 1); }
        SBAR();
        WAITL();
        __builtin_amdgcn_s_setprio(1);
#pragma unroll
        for (int i = 0; i < nI; i++) {
            acc[i][2] = mfma16(av[i], bv[0], acc[i][2]);
            acc[i][3] = mfma16(av[i], bv[1], acc[i][3]);
        }
        __builtin_amdgcn_s_setprio(0);
        if (t + 1 < nt) { if constexpr (BMQ == 2) WAITV(8); else WAITV(6); }
        else { WAITV(0); }
        SBAR();

#pragma unroll
        for (int i = 0; i < nI; i++) av[i] = *(const f16x8*)(buf + ACH + aoff + i * 1024);
        bv[0] = *(const f16x8*)(buf + 16384 + boff);
        bv[1] = *(const f16x8*)(buf + 16384 + boff + 1024);
        SBAR();
        WAITL();
        __builtin_amdgcn_s_setprio(1);
#pragma unroll
        for (int i = 0; i < nI; i++) {
            acc[i][0] = mfma16(av[i], bv[0], acc[i][0]);
            acc[i][1] = mfma16(av[i], bv[1], acc[i][1]);
        }
        __builtin_amdgcn_s_setprio(0);
        SBAR();

        bv[0] = *(const f16x8*)(buf + 16384 + boff + 2048);
        bv[1] = *(const f16x8*)(buf + 16384 + boff + 3072);
        SBAR();
        WAITL();
        __builtin_amdgcn_s_setprio(1);
#pragma unroll
        for (int i = 0; i < nI; i++) {
            acc[i][2] = mfma16(av[i], bv[0], acc[i][2]);
            acc[i][3] = mfma16(av[i], bv[1], acc[i][3]);
        }
        __builtin_amdgcn_s_setprio(0);
        if (t + 1 < nt) { WAITV(2); } else { WAITV(0); }
        SBAR();
    }

    if constexpr (OUT_MODE == 2) {
        auto tr = (f16(*)[72])smraw;
        const int batch = (int)(rowA0 >> 11);
        const long long rib = rowA0 & 2047;
        const int c  = tid >> 1;
        const int r0 = (tid & 1) << 5;
#pragma unroll
        for (int h2 = 0; h2 < 2; h2++)
#pragma unroll
            for (int iq = 0; iq < 2; iq++) {
                __syncthreads();
                if (wm == h2) {
#pragma unroll
                    for (int i2 = 0; i2 < 4; i2++)
#pragma unroll
                        for (int j = 0; j < 4; j++)
#pragma unroll
                            for (int e = 0; e < 4; e++)
                                tr[wn * 64 + j * 16 + l16][i2 * 16 + quad * 4 + e] =
                                    (f16)acc[iq * 4 + i2][j][e];
                }
                __syncthreads();
                f16* vt = Ch + (long long)batch * 1024 * 2048 +
                          (long long)(colB0 + c) * ldc + rib + h2 * 128 + iq * 64 + r0;
#pragma unroll
                for (int u = 0; u < 32; u += 8)
                    *(f16x8*)(vt + u) = *(const f16x8*)&tr[c][r0 + u];
            }
        return;
    }

    const long long cOff = (long long)bz * sC +
                           (rowA0 + wm * (BMQ * 64) + quad * 4) * (long long)ldc +
                           colB0 + wn * 64 + l16;
#pragma unroll
    for (int i = 0; i < nI; i++)
#pragma unroll
        for (int e = 0; e < 4; e++) {
            const long long ro = cOff + (long long)(i * 16 + e) * ldc;
            if (OUT_MODE == 0) {
                float* rp = Cf + ro;
#pragma unroll
                for (int j = 0; j < 4; j++) rp[j * 16] = acc[i][j][e];
            } else {
                f16* rp = Ch + ro;
#pragma unroll
                for (int j = 0; j < 4; j++) rp[j * 16] = (f16)acc[i][j][e];
            }
        }
}

__global__ __launch_bounds__(512, 2) void tv8d(
    const f16* __restrict__ Xf, const f16* __restrict__ Mt_f,
    const f16* __restrict__ Wvt_f, f16* __restrict__ T, f16* __restrict__ Vt)
{
    extern __shared__ char smraw[];
    int bx = blockIdx.x, by = blockIdx.y;
    xcd_swz(256, 8, bx, by);
    if (bx < 4)
        gemm_deep_body<1, 2>(smraw, Xf, Mt_f, nullptr, T, 1024, 1024, 1024, 1024,
                             0, 0, 0, bx, by, 0);
    else
        gemm_deep_body<2, 2>(smraw, Xf, Wvt_f, nullptr, Vt, 1024, 1024, 1024, 2048,
                             0, 0, 0, bx - 4, by, 0);
}

// ---- D1: X->f16 || Wq,Wk bf16-split || Wv transpose->f16 ----
__global__ __launch_bounds__(256) void prep_all(
    const float4* __restrict__ X, f16* __restrict__ Xf,
    const float* __restrict__ Wq, const float* __restrict__ Wk, const float* __restrict__ Wv,
    bf16* __restrict__ Wq_h, bf16* __restrict__ Wq_l,
    bf16* __restrict__ Wk_h, bf16* __restrict__ Wk_l,
    f16* __restrict__ Wvt_f)
{
    int b = blockIdx.x;
    if (b < 8192) {
        long long i = (long long)b * 256 + threadIdx.x;
        float4 v = X[i];
        f16x4 fv = {(f16)v.x, (f16)v.y, (f16)v.z, (f16)v.w};
        *(f16x4*)(Xf + 4 * i) = fv;
    } else if (b < 10240) {
        const int b2 = b - 8192;
        const float4* W = (const float4*)(b2 < 1024 ? Wq : Wk);
        bf16* hh = b2 < 1024 ? Wq_h : Wk_h;
        bf16* ll = b2 < 1024 ? Wq_l : Wk_l;
        long long i = (long long)(b2 & 1023) * 256 + threadIdx.x;
        float4 v = W[i];
        bf16 a0 = (bf16)v.x, a1 = (bf16)v.y, a2 = (bf16)v.z, a3 = (bf16)v.w;
        bf16x4 hv = {a0, a1, a2, a3};
        bf16x4 lv = {(bf16)(v.x - (float)a0), (bf16)(v.y - (float)a1),
                     (bf16)(v.z - (float)a2), (bf16)(v.w - (float)a3)};
        *(bf16x4*)(hh + 4 * i) = hv;
        *(bf16x4*)(ll + 4 * i) = lv;
    } else {
        const int b3 = b - 10240;
        __shared__ float t[32][33];
        const int bx = (b3 & 31) * 32, by = (b3 >> 5) * 32;
        const int tx = threadIdx.x & 31, ty = threadIdx.x >> 5;
#pragma unroll
        for (int i = 0; i < 32; i += 8)
            t[ty + i][tx] = Wv[(long long)(by + ty + i) * 1024 + bx + tx];
        __syncthreads();
#pragma unroll
        for (int i = 0; i < 32; i += 8) {
            long long o = (long long)(bx + ty + i) * 1024 + by + tx;
            Wvt_f[o] = (f16)t[tx][ty + i];
        }
    }
}

// ---- D5: row softmax fp32 -> f16, vectorized ----
__global__ __launch_bounds__(256) void softmax_f16(const float* __restrict__ S,
                                                   f16* __restrict__ P, int n)
{
    const long long row = blockIdx.x;
    const float4* p = (const float4*)(S + row * (long long)n);
    f16* q = P + row * (long long)n;
    const int tid = threadIdx.x;
    const int wv = tid >> 6, lane = tid & 63;

    float4 va = p[tid], vb = p[tid + 256];
    float v[8] = {va.x, va.y, va.z, va.w, vb.x, vb.y, vb.z, vb.w};
    float m = -3.4e38f;
#pragma unroll
    for (int i = 0; i < 8; i++) m = fmaxf(m, v[i]);
#pragma unroll
    for (int off = 32; off > 0; off >>= 1) m = fmaxf(m, __shfl_xor(m, off, 64));

    __shared__ float red[4];
    if (lane == 0) red[wv] = m;
    __syncthreads();
    m = fmaxf(fmaxf(red[0], red[1]), fmaxf(red[2], red[3]));

    float s = 0.f;
#pragma unroll
    for (int i = 0; i < 8; i++) { v[i] = __expf(v[i] - m); s += v[i]; }
#pragma unroll
    for (int off = 32; off > 0; off >>= 1) s += __shfl_xor(s, off, 64);
    __syncthreads();
    if (lane == 0) red[wv] = s;
    __syncthreads();
    s = red[0] + red[1] + red[2] + red[3];

    const float inv = 1.0f / s;
    f16x4 o0 = {(f16)(v[0] * inv), (f16)(v[1] * inv), (f16)(v[2] * inv), (f16)(v[3] * inv)};
    f16x4 o1 = {(f16)(v[4] * inv), (f16)(v[5] * inv), (f16)(v[6] * inv), (f16)(v[7] * inv)};
    *(f16x4*)(q + tid * 4) = o0;
    *(f16x4*)(q + 1024 + tid * 4) = o1;
}

extern "C" void kernel_launch(void* const* d_in, const int* in_sizes, int n_in,
                              void* d_out, int out_size, void* d_ws, size_t ws_size,
                              hipStream_t stream) {
    const float* X  = (const float*)d_in[0];   // [8192,1024]
    const float* Wq = (const float*)d_in[1];   // [1024,1024]
    const float* Wk = (const float*)d_in[2];
    const float* Wv = (const float*)d_in[3];
    float* out = (float*)d_out;                // [8192,1024]

    char* w = (char*)d_ws;
    const long long MB = 1024LL * 1024;
    f16*  Xf    = (f16*) (w + 0 * MB);     // 16 MB
    bf16* Wq_h  = (bf16*)(w + 16 * MB);    // 2 MB
    bf16* Wq_l  = (bf16*)(w + 18 * MB);
    bf16* Wk_h  = (bf16*)(w + 20 * MB);
    bf16* Wk_l  = (bf16*)(w + 22 * MB);
    f16*  Wvt_f = (f16*) (w + 24 * MB);    // 2 MB (transposed)
    f16*  Mt_f  = (f16*) (w + 26 * MB);    // 2 MB
    f16*  T     = (f16*) (w + 28 * MB);    // 16 MB [8192,1024]
    f16*  Vt    = (f16*) (w + 44 * MB);    // 16 MB [4][1024][2048]
    float* Sc   = (float*)(w + 60 * MB);   // 64 MB
    f16*  P     = (f16*) (w + 124 * MB);   // 32 MB -> ends 156 MB

    static int deep_ok = -1;
    if (deep_ok < 0) {
        hipError_t e1 = hipFuncSetAttribute(
            reinterpret_cast<const void*>(tv8d),
            hipFuncAttributeMaxDynamicSharedMemorySize, 131072);
        deep_ok = (e1 == hipSuccess) ? 1 : 0;
    }

    dim3 blk(256);

    // D1: prep
    prep_all<<<dim3(11264), blk, 0, stream>>>(
        (const float4*)X, Xf, Wq, Wk, Wv, Wq_h, Wq_l, Wk_h, Wk_l, Wvt_f);

    // D2: Mt = Wk_s Wq_s^T (split bf16, 3-MFMA) -> f16
    gemm_bt<bf16, true, 1, 32><<<dim3(8, 8, 1), blk, 32768, stream>>>(
        Wk_h, Wk_l, Wq_h, Wq_l, nullptr, Mt_f,
        1024, 1024, 1024, 1024, 0, 0, 0);

    // D3: T || Vt — deep comparator (fallback: R2-verified light pair)
    if (deep_ok)
        tv8d<<<dim3(8, 32), dim3(512), 131072, stream>>>(Xf, Mt_f, Wvt_f, T, Vt);
    else
        tv_gemm<<<dim3(16, 64), blk, 33280, stream>>>(Xf, Mt_f, Wvt_f, T, Vt);

    // D4: Sc = T . Xf^T per batch -> fp32  [LIGHT: 128^2, 16KB, 1024 blocks]
    gemm_lt<0><<<dim3(16, 16, 4), blk, 16384, stream>>>(
        T, Xf, Sc, nullptr, 1024, 1024, 1024, 2048,
        2048LL * 1024, 2048LL * 1024, 2048LL * 2048);

    // D5: softmax rows -> f16 P
    softmax_f16<<<dim3(4 * 2048), blk, 0, stream>>>(Sc, P, 2048);

    // D6: out = P . Vt^T  [LIGHT: 128^2, 16KB, 512 blocks]
    gemm_lt<0><<<dim3(8, 16, 4), blk, 16384, stream>>>(
        P, Vt, out, nullptr, 2048, 2048, 2048, 1024,
        2048LL * 2048, 1024LL * 2048, 2048LL * 1024);
}

// Round 10
// 271.923 us; speedup vs baseline: 2.0993x; 1.1413x over previous
//
#include <hip/hip_runtime.h>
#include <math.h>

// Round 18: R17 resubmit with compile fix (bf16 mfma16 overload had a stray
// "builtin == nullptr" expression; builtins must be directly called).
// The A/B vs R14/R6 (275us) remains: REMOVE sched_barrier(0) from all
// barrier/waitcnt macros (m141: order-pinning defeats compiler scheduler,
// 0.58x). SBAR = plain s_barrier; WAITL = bare lgkmcnt(0); WAITV keeps
// "memory" clobber only (prevents next-buffer LDS reads hoisting above
// write certification). Kernels otherwise byte-identical to R14 deep config:
//   D1 prep_all : X->f16 || Wq,Wk bf16-split || Wv transpose->f16
//   D2 mt       : Mt = Wk_s Wq_s^T (split-bf16 3-MFMA, 128^2) -> f16
//   D3 tv8d     : T || Vt (deep 256^2, 128KB)
//   D4 scd      : Sc = T . Xf^T -> fp32 (deep)
//   D5 softmax  : P = softmax(Sc) -> f16
//   D6 pvd      : out = P . Vt^T (deep BM=128, 96KB)

typedef __bf16 bf16;
typedef _Float16 f16;
typedef __bf16 bf16x8 __attribute__((ext_vector_type(8)));
typedef __bf16 bf16x4 __attribute__((ext_vector_type(4)));
typedef _Float16 f16x4 __attribute__((ext_vector_type(4)));
typedef _Float16 f16x8 __attribute__((ext_vector_type(8)));
typedef float  f32x4  __attribute__((ext_vector_type(4)));

template<typename E> struct vec8_of;
template<> struct vec8_of<bf16> { using type = bf16x8; };
template<> struct vec8_of<f16>  { using type = f16x8; };

__device__ inline f32x4 mfma16(bf16x8 a, bf16x8 b, f32x4 c) {
    return __builtin_amdgcn_mfma_f32_16x16x32_bf16(a, b, c, 0, 0, 0);
}
__device__ inline f32x4 mfma16(f16x8 a, f16x8 b, f32x4 c) {
    return __builtin_amdgcn_mfma_f32_16x16x32_f16(a, b, c, 0, 0, 0);
}

#define AS1 __attribute__((address_space(1)))
#define AS3 __attribute__((address_space(3)))

template<typename E>
__device__ inline void async_load16(const E* g, void* l) {
    __builtin_amdgcn_global_load_lds((const AS1 unsigned int*)g,
                                     (AS3 unsigned int*)l, 16, 0, 0);
}

// ---- m201 discipline: NO sched_barrier pinning ----
#define SBAR()   __builtin_amdgcn_s_barrier()
#define WAITV(n) asm volatile("s_waitcnt vmcnt(" #n ")" ::: "memory")
#define WAITL()  asm volatile("s_waitcnt lgkmcnt(0)")

// XCD-aware bijective tile swizzle (nwg % 8 == 0).
__device__ inline void xcd_swz(int nwg, int gx, int& bx, int& by) {
    const int flat = by * gx + bx;
    const int s = (flat & 7) * (nwg >> 3) + (flat >> 3);
    bx = s % gx;
    by = s / gx;
}

// ================= deep (BMQ*128)x256 f16 GEMM (R14 schedule) ==============
template<int OUT_MODE, int BMQ>
__device__ __forceinline__ void gemm_deep_body(
    char* __restrict__ smraw,
    const f16* __restrict__ A, const f16* __restrict__ B,
    float* __restrict__ Cf, f16* __restrict__ Ch,
    int K, int lda, int ldb, int ldc,
    long long sA, long long sB, long long sC,
    int bx, int by, int bz)
{
    constexpr int ACH   = BMQ * 8192;
    constexpr int BOFF  = 2 * ACH;
    constexpr int BUFSZ = 2 * ACH + 32768;
    constexpr int nI    = 4 * BMQ;

    A += (long long)bz * sA;
    B += (long long)bz * sB;

    const int tid  = threadIdx.x;
    const int lane = tid & 63;
    const int wave = tid >> 6;
    const int quad = lane >> 4;
    const int l16  = lane & 15;
    const int wm   = wave >> 2;
    const int wn   = wave & 3;

    const long long rowA0 = (long long)by * (BMQ * 128);
    const long long colB0 = (long long)bx * 256;

    const int line0 = tid >> 3;
    const int slog  = (tid & 7) ^ (line0 & 7);
    const int r0s   = line0 * 2 + (slog >> 2);
    const int c0s   = (slog & 3) * 8;

    const f16* aSrc0 = A + (rowA0 + r0s) * lda + c0s;
    const f16* aSrc1 = A + (rowA0 + 128 + r0s) * lda + c0s;
    const f16* bSrc0 = B + (colB0 + r0s) * ldb + c0s;
    const f16* bSrc1 = B + (colB0 + 128 + r0s) * ldb + c0s;

    const int nt = K >> 6;

    auto stageA = [&](int t, int kh) {
        char* dst = smraw + (t & 1) * BUFSZ + kh * ACH;
        const int k0 = t * 64 + kh * 32;
        async_load16(aSrc0 + k0, dst + tid * 16);
        if constexpr (BMQ == 2) async_load16(aSrc1 + k0, dst + 8192 + tid * 16);
    };
    auto stageB = [&](int t, int kh) {
        char* dst = smraw + (t & 1) * BUFSZ + BOFF + kh * 16384;
        const int k0 = t * 64 + kh * 32;
        async_load16(bSrc0 + k0, dst + tid * 16);
        async_load16(bSrc1 + k0, dst + 8192 + tid * 16);
    };

    const int h    = l16 >> 1;
    const int lofs = h * 128 + ((((l16 & 1) * 4 + quad) ^ h) << 4);
    const int aoff = wm * (ACH / 2) + lofs;
    const int boff = BOFF + wn * 4096 + lofs;

    f32x4 acc[nI][4];
#pragma unroll
    for (int i = 0; i < nI; i++)
#pragma unroll
        for (int j = 0; j < 4; j++) acc[i][j] = (f32x4){0.f, 0.f, 0.f, 0.f};

    stageA(0, 0); stageA(0, 1); stageB(0, 0); stageB(0, 1);
    WAITV(2);
    SBAR();

    for (int t = 0; t < nt; t++) {
        const char* buf = smraw + (t & 1) * BUFSZ;
        f16x8 av[nI], bv[2];

        // ---- p0: A-kh0 + B(j01,kh0); stage A(t+1); 16 MFMA ----
#pragma unroll
        for (int i = 0; i < nI; i++) av[i] = *(const f16x8*)(buf + aoff + i * 1024);
        bv[0] = *(const f16x8*)(buf + boff);
        bv[1] = *(const f16x8*)(buf + boff + 1024);
        if (t + 1 < nt) { stageA(t + 1, 0); stageA(t + 1, 1); }
        SBAR();
        WAITL();
        __builtin_amdgcn_s_setprio(1);
#pragma unroll
        for (int i = 0; i < nI; i++) {
            acc[i][0] = mfma16(av[i], bv[0], acc[i][0]);
            acc[i][1] = mfma16(av[i], bv[1], acc[i][1]);
        }
        __builtin_amdgcn_s_setprio(0);
        SBAR();

        // ---- p1: B(j23,kh0); stage B(t+1); 16 MFMA; certify B-kh1(t) ----
        bv[0] = *(const f16x8*)(buf + boff + 2048);
        bv[1] = *(const f16x8*)(buf + boff + 3072);
        if (t + 1 < nt) { stageB(t + 1, 0); stageB(t + 1, 1); }
        SBAR();
        WAITL();
        __builtin_amdgcn_s_setprio(1);
#pragma unroll
        for (int i = 0; i < nI; i++) {
            acc[i][2] = mfma16(av[i], bv[0], acc[i][2]);
            acc[i][3] = mfma16(av[i], bv[1], acc[i][3]);
        }
        __builtin_amdgcn_s_setprio(0);
        if (t + 1 < nt) { if constexpr (BMQ == 2) WAITV(8); else WAITV(6); }
        else { WAITV(0); }
        SBAR();

        // ---- p2: A-kh1 + B(j01,kh1); 16 MFMA ----
#pragma unroll
        for (int i = 0; i < nI; i++) av[i] = *(const f16x8*)(buf + ACH + aoff + i * 1024);
        bv[0] = *(const f16x8*)(buf + 16384 + boff);
        bv[1] = *(const f16x8*)(buf + 16384 + boff + 1024);
        SBAR();
        WAITL();
        __builtin_amdgcn_s_setprio(1);
#pragma unroll
        for (int i = 0; i < nI; i++) {
            acc[i][0] = mfma16(av[i], bv[0], acc[i][0]);
            acc[i][1] = mfma16(av[i], bv[1], acc[i][1]);
        }
        __builtin_amdgcn_s_setprio(0);
        SBAR();

        // ---- p3: B(j23,kh1); 16 MFMA; certify A,B-kh0(t+1) ----
        bv[0] = *(const f16x8*)(buf + 16384 + boff + 2048);
        bv[1] = *(const f16x8*)(buf + 16384 + boff + 3072);
        SBAR();
        WAITL();
        __builtin_amdgcn_s_setprio(1);
#pragma unroll
        for (int i = 0; i < nI; i++) {
            acc[i][2] = mfma16(av[i], bv[0], acc[i][2]);
            acc[i][3] = mfma16(av[i], bv[1], acc[i][3]);
        }
        __builtin_amdgcn_s_setprio(0);
        if (t + 1 < nt) { WAITV(2); } else { WAITV(0); }
        SBAR();
    }

    if constexpr (OUT_MODE == 2) {
        auto tr = (f16(*)[72])smraw;
        const int batch = (int)(rowA0 >> 11);
        const long long rib = rowA0 & 2047;
        const int c  = tid >> 1;
        const int r0 = (tid & 1) << 5;
#pragma unroll
        for (int h2 = 0; h2 < 2; h2++)
#pragma unroll
            for (int iq = 0; iq < 2; iq++) {
                __syncthreads();
                if (wm == h2) {
#pragma unroll
                    for (int i2 = 0; i2 < 4; i2++)
#pragma unroll
                        for (int j = 0; j < 4; j++)
#pragma unroll
                            for (int e = 0; e < 4; e++)
                                tr[wn * 64 + j * 16 + l16][i2 * 16 + quad * 4 + e] =
                                    (f16)acc[iq * 4 + i2][j][e];
                }
                __syncthreads();
                f16* vt = Ch + (long long)batch * 1024 * 2048 +
                          (long long)(colB0 + c) * ldc + rib + h2 * 128 + iq * 64 + r0;
#pragma unroll
                for (int u = 0; u < 32; u += 8)
                    *(f16x8*)(vt + u) = *(const f16x8*)&tr[c][r0 + u];
            }
        return;
    }

    const long long cOff = (long long)bz * sC +
                           (rowA0 + wm * (BMQ * 64) + quad * 4) * (long long)ldc +
                           colB0 + wn * 64 + l16;
#pragma unroll
    for (int i = 0; i < nI; i++)
#pragma unroll
        for (int e = 0; e < 4; e++) {
            const long long ro = cOff + (long long)(i * 16 + e) * ldc;
            if (OUT_MODE == 0) {
                float* rp = Cf + ro;
#pragma unroll
                for (int j = 0; j < 4; j++) rp[j * 16] = acc[i][j][e];
            } else {
                f16* rp = Ch + ro;
#pragma unroll
                for (int j = 0; j < 4; j++) rp[j * 16] = (f16)acc[i][j][e];
            }
        }
}

__global__ __launch_bounds__(512, 2) void tv8d(
    const f16* __restrict__ Xf, const f16* __restrict__ Mt_f,
    const f16* __restrict__ Wvt_f, f16* __restrict__ T, f16* __restrict__ Vt)
{
    extern __shared__ char smraw[];
    int bx = blockIdx.x, by = blockIdx.y;
    xcd_swz(256, 8, bx, by);
    if (bx < 4)
        gemm_deep_body<1, 2>(smraw, Xf, Mt_f, nullptr, T, 1024, 1024, 1024, 1024,
                             0, 0, 0, bx, by, 0);
    else
        gemm_deep_body<2, 2>(smraw, Xf, Wvt_f, nullptr, Vt, 1024, 1024, 1024, 2048,
                             0, 0, 0, bx - 4, by, 0);
}

template<int OUT_MODE, int BMQ>
__global__ __launch_bounds__(512, 2) void gemmd_k(
    const f16* __restrict__ A, const f16* __restrict__ B,
    float* __restrict__ Cf, f16* __restrict__ Ch,
    int K, int lda, int ldb, int ldc,
    long long sA, long long sB, long long sC)
{
    extern __shared__ char smraw[];
    int bx = blockIdx.x, by = blockIdx.y;
    xcd_swz(gridDim.x * gridDim.y, gridDim.x, bx, by);
    gemm_deep_body<OUT_MODE, BMQ>(smraw, A, B, Cf, Ch, K, lda, ldb, ldc,
                                  sA, sB, sC, bx, by, blockIdx.z);
}

// ============ 64KB fallback kernels (R13-verified; run only if attr fails) ==
template<int OUT_MODE, int BMQ>
__device__ __forceinline__ void gemm8_body(
    char* __restrict__ smraw,
    const f16* __restrict__ A, const f16* __restrict__ B,
    float* __restrict__ Cf, f16* __restrict__ Ch,
    int K, int lda, int ldb, int ldc,
    long long sA, long long sB, long long sC,
    int bx, int by, int bz)
{
    constexpr int B0OFF = BMQ * 8192;
    constexpr int B1OFF = B0OFF + 8192;
    constexpr int BUFSZ = B0OFF + 16384;

    A += (long long)bz * sA;
    B += (long long)bz * sB;

    const int tid  = threadIdx.x;
    const int lane = tid & 63;
    const int wave = tid >> 6;
    const int quad = lane >> 4;
    const int l16  = lane & 15;
    const int wm   = wave >> 2;
    const int wn   = wave & 3;

    const long long rowA0 = (long long)by * (BMQ * 128);
    const long long colB0 = (long long)bx * 256;

    const int line0 = tid >> 3;
    const int slog  = (tid & 7) ^ (line0 & 7);
    const int aRow0 = line0 * 2 + (slog >> 2);
    const int aCol0 = (slog & 3) * 8;
    const int bRow  = ((aRow0 >> 5) << 6) + (aRow0 & 31);

    const f16* aSrc0 = A + (rowA0 + aRow0) * lda + aCol0;
    const f16* aSrc1 = A + (rowA0 + 128 + aRow0) * lda + aCol0;
    const f16* b0Src = B + (colB0 + bRow) * ldb + aCol0;
    const f16* b1Src = b0Src + 32LL * ldb;

    const int dA0 = tid * 16, dA1 = 8192 + tid * 16;

    const int nt = K >> 5;

    auto stageA = [&](int t) {
        char* buf = smraw + (t & 1) * BUFSZ;
        async_load16(aSrc0 + t * 32, buf + dA0);
        if (BMQ == 2) async_load16(aSrc1 + t * 32, buf + dA1);
    };
    auto stageB0 = [&](int t) {
        char* buf = smraw + (t & 1) * BUFSZ;
        async_load16(b0Src + t * 32, buf + B0OFF + dA0);
    };
    auto stageB1 = [&](int t) {
        char* buf = smraw + (t & 1) * BUFSZ;
        async_load16(b1Src + t * 32, buf + B1OFF + dA0);
    };

    const int h    = l16 >> 1;
    const int lofs = h * 128 + ((((l16 & 1) * 4 + quad) ^ h) << 4);
    const int aoff = wm * (BMQ * 4096) + lofs;
    const int boff = wn * 2048 + lofs;

    f32x4 acc[4 * BMQ][4];
#pragma unroll
    for (int i = 0; i < 4 * BMQ; i++)
#pragma unroll
        for (int j = 0; j < 4; j++) acc[i][j] = (f32x4){0.f, 0.f, 0.f, 0.f};

    stageA(0); stageB0(0); stageB1(0);
    stageA(1); stageB0(1);
    if constexpr (BMQ == 2) WAITV(4); else WAITV(3);
    SBAR();

    for (int t = 0; t < nt; t++) {
        const char* buf = smraw + (t & 1) * BUFSZ;
        f16x8 av[4 * BMQ], bv[2];

#pragma unroll
        for (int i = 0; i < 4 * BMQ; i++) av[i] = *(const f16x8*)(buf + aoff + i * 1024);
#pragma unroll
        for (int j = 0; j < 2; j++) bv[j] = *(const f16x8*)(buf + B0OFF + boff + j * 1024);
        if (t + 1 < nt) stageB1(t + 1);
        SBAR();
        WAITL();
        __builtin_amdgcn_s_setprio(1);
#pragma unroll
        for (int i = 0; i < 4 * BMQ; i++) {
            acc[i][0] = mfma16(av[i], bv[0], acc[i][0]);
            acc[i][1] = mfma16(av[i], bv[1], acc[i][1]);
        }
        __builtin_amdgcn_s_setprio(0);
        if (t + 1 < nt) { if constexpr (BMQ == 2) WAITV(4); else WAITV(3); }
        else WAITV(0);
        SBAR();

#pragma unroll
        for (int j = 0; j < 2; j++) bv[j] = *(const f16x8*)(buf + B1OFF + boff + j * 1024);
        if (t + 2 < nt) { stageA(t + 2); stageB0(t + 2); }
        SBAR();
        WAITL();
        __builtin_amdgcn_s_setprio(1);
#pragma unroll
        for (int i = 0; i < 4 * BMQ; i++) {
            acc[i][2] = mfma16(av[i], bv[0], acc[i][2]);
            acc[i][3] = mfma16(av[i], bv[1], acc[i][3]);
        }
        __builtin_amdgcn_s_setprio(0);
        if (t + 2 < nt) { if constexpr (BMQ == 2) WAITV(4); else WAITV(3); }
        else if (t + 1 < nt) WAITV(1);
        SBAR();
    }

    if constexpr (OUT_MODE == 2) {
        auto tr = (f16(*)[72])smraw;
        const int batch = (int)(rowA0 >> 11);
        const long long rib = rowA0 & 2047;
        const int c  = tid >> 1;
        const int r0 = (tid & 1) << 5;
#pragma unroll
        for (int h2 = 0; h2 < 2; h2++)
#pragma unroll
            for (int iq = 0; iq < 2; iq++) {
                __syncthreads();
                if (wm == h2) {
#pragma unroll
                    for (int i2 = 0; i2 < 4; i2++)
#pragma unroll
                        for (int j = 0; j < 4; j++)
#pragma unroll
                            for (int e = 0; e < 4; e++)
                                tr[wn * 64 + j * 16 + l16][i2 * 16 + quad * 4 + e] =
                                    (f16)acc[iq * 4 + i2][j][e];
                }
                __syncthreads();
                f16* vt = Ch + (long long)batch * 1024 * 2048 +
                          (long long)(colB0 + c) * ldc + rib + h2 * 128 + iq * 64 + r0;
#pragma unroll
                for (int u = 0; u < 32; u += 8)
                    *(f16x8*)(vt + u) = *(const f16x8*)&tr[c][r0 + u];
            }
        return;
    }

    const long long cOff = (long long)bz * sC +
                           (rowA0 + wm * (BMQ * 64) + quad * 4) * (long long)ldc +
                           colB0 + wn * 64 + l16;
#pragma unroll
    for (int i = 0; i < 4 * BMQ; i++)
#pragma unroll
        for (int e = 0; e < 4; e++) {
            const long long ro = cOff + (long long)(i * 16 + e) * ldc;
            if (OUT_MODE == 0) {
                float* rp = Cf + ro;
#pragma unroll
                for (int j = 0; j < 4; j++) rp[j * 16] = acc[i][j][e];
            } else {
                f16* rp = Ch + ro;
#pragma unroll
                for (int j = 0; j < 4; j++) rp[j * 16] = (f16)acc[i][j][e];
            }
        }
}

__global__ __launch_bounds__(512, 2) void tv8(
    const f16* __restrict__ Xf, const f16* __restrict__ Mt_f,
    const f16* __restrict__ Wvt_f, f16* __restrict__ T, f16* __restrict__ Vt)
{
    extern __shared__ char smraw[];
    int bx = blockIdx.x, by = blockIdx.y;
    xcd_swz(256, 8, bx, by);
    if (bx < 4)
        gemm8_body<1, 2>(smraw, Xf, Mt_f, nullptr, T, 1024, 1024, 1024, 1024,
                         0, 0, 0, bx, by, 0);
    else
        gemm8_body<2, 2>(smraw, Xf, Wvt_f, nullptr, Vt, 1024, 1024, 1024, 2048,
                         0, 0, 0, bx - 4, by, 0);
}

template<int OUT_MODE, int BMQ>
__global__ __launch_bounds__(512, 2) void gemm8_k(
    const f16* __restrict__ A, const f16* __restrict__ B,
    float* __restrict__ Cf, f16* __restrict__ Ch,
    int K, int lda, int ldb, int ldc,
    long long sA, long long sB, long long sC)
{
    extern __shared__ char smraw[];
    int bx = blockIdx.x, by = blockIdx.y;
    xcd_swz(gridDim.x * gridDim.y, gridDim.x, bx, by);
    gemm8_body<OUT_MODE, BMQ>(smraw, A, B, Cf, Ch, K, lda, ldb, ldc, sA, sB, sC,
                              bx, by, blockIdx.z);
}

// ============== 128^2 kernel (Mt only: split-bf16 3-MFMA) — verified ========
template<typename E, bool SPLIT, int OUT_MODE, int BK>
__device__ __forceinline__ void gemm_body(
    char* __restrict__ smraw,
    const E* __restrict__ Ahi, const E* __restrict__ Alo,
    const E* __restrict__ Bhi, const E* __restrict__ Blo,
    float* __restrict__ Cf, f16* __restrict__ Ch,
    int K, int lda, int ldb, int ldc,
    long long sA, long long sB, long long sC,
    int bx, int by, int bz)
{
    using vec8 = typename vec8_of<E>::type;
    constexpr int TILE_BYTES = 128 * BK * (int)sizeof(E);
    constexpr int CPW = (TILE_BYTES / 1024) / 4;
    constexpr int SPR = (BK * (int)sizeof(E)) / 16;

    Ahi += (long long)bz * sA;
    Bhi += (long long)bz * sB;
    if (SPLIT) { Alo += (long long)bz * sA; Blo += (long long)bz * sB; }

    const int tid  = threadIdx.x;
    const int lane = tid & 63;
    const int wave = tid >> 6;
    const int quad = lane >> 4;
    const int l16  = lane & 15;
    const int wm   = (wave >> 1) * 64;
    const int wn   = (wave & 1) * 64;

    const long long rowA0 = (long long)by * 128;
    const long long colB0 = (long long)bx * 128;

    auto swz = [](int r) -> int { return (SPR == 8) ? (r & 7) : ((r >> 1) & 3); };

    int ofs[CPW], rr[CPW], cc8[CPW];
#pragma unroll
    for (int u = 0; u < CPW; u++) {
        ofs[u] = (wave * CPW + u) * 1024 + lane * 16;
        const int s = ofs[u] >> 4;
        rr[u]  = s / SPR;
        cc8[u] = (s & (SPR - 1)) ^ swz(rr[u]);
    }

    f32x4 acc[4][4];
#pragma unroll
    for (int i = 0; i < 4; i++)
#pragma unroll
        for (int j = 0; j < 4; j++) acc[i][j] = (f32x4){0.f, 0.f, 0.f, 0.f};

    for (int k0 = 0; k0 < K; k0 += BK) {
#pragma unroll
        for (int u = 0; u < CPW; u++) {
            async_load16(Ahi + (rowA0 + rr[u]) * lda + k0 + cc8[u] * 8, smraw + 0 * TILE_BYTES + ofs[u]);
            async_load16(Bhi + (colB0 + rr[u]) * ldb + k0 + cc8[u] * 8, smraw + 1 * TILE_BYTES + ofs[u]);
            if (SPLIT) {
                async_load16(Alo + (rowA0 + rr[u]) * lda + k0 + cc8[u] * 8, smraw + 2 * TILE_BYTES + ofs[u]);
                async_load16(Blo + (colB0 + rr[u]) * ldb + k0 + cc8[u] * 8, smraw + 3 * TILE_BYTES + ofs[u]);
            }
        }
        __syncthreads();

#pragma unroll
        for (int kh = 0; kh < BK / 32; kh++) {
            const int kc8 = kh * 4 + quad;
            vec8 a_hi[4], b_hi[4], a_lo[4], b_lo[4];
#pragma unroll
            for (int i = 0; i < 4; i++) {
                const int ra = wm + i * 16 + l16;
                const int rb = wn + i * 16 + l16;
                const int oa = ra * (SPR * 16) + ((kc8 ^ swz(ra)) << 4);
                const int ob = rb * (SPR * 16) + ((kc8 ^ swz(rb)) << 4);
                a_hi[i] = *(const vec8*)(smraw + 0 * TILE_BYTES + oa);
                b_hi[i] = *(const vec8*)(smraw + 1 * TILE_BYTES + ob);
                if (SPLIT) {
                    a_lo[i] = *(const vec8*)(smraw + 2 * TILE_BYTES + oa);
                    b_lo[i] = *(const vec8*)(smraw + 3 * TILE_BYTES + ob);
                }
            }
#pragma unroll
            for (int i = 0; i < 4; i++)
#pragma unroll
                for (int j = 0; j < 4; j++) {
                    acc[i][j] = mfma16(a_hi[i], b_hi[j], acc[i][j]);
                    if (SPLIT) {
                        acc[i][j] = mfma16(a_hi[i], b_lo[j], acc[i][j]);
                        acc[i][j] = mfma16(a_lo[i], b_hi[j], acc[i][j]);
                    }
                }
        }
        __syncthreads();
    }

    const long long cOff = (long long)bz * sC +
                           (rowA0 + wm + quad * 4) * (long long)ldc + colB0 + wn + l16;
#pragma unroll
    for (int i = 0; i < 4; i++)
#pragma unroll
        for (int e = 0; e < 4; e++) {
            const long long ro = cOff + (i * 16 + e) * ldc;
            if (OUT_MODE == 0) {
                float* rp = Cf + ro;
#pragma unroll
                for (int j = 0; j < 4; j++) rp[j * 16] = acc[i][j][e];
            } else {
                f16* rp = Ch + ro;
#pragma unroll
                for (int j = 0; j < 4; j++) rp[j * 16] = (f16)acc[i][j][e];
            }
        }
}

template<typename E, bool SPLIT, int OUT_MODE, int BK>
__global__ __launch_bounds__(256) void gemm_bt(
    const E* __restrict__ Ahi, const E* __restrict__ Alo,
    const E* __restrict__ Bhi, const E* __restrict__ Blo,
    float* __restrict__ Cf, f16* __restrict__ Ch,
    int K, int lda, int ldb, int ldc,
    long long sA, long long sB, long long sC)
{
    extern __shared__ char smraw[];
    gemm_body<E, SPLIT, OUT_MODE, BK>(smraw, Ahi, Alo, Bhi, Blo, Cf, Ch,
                                      K, lda, ldb, ldc, sA, sB, sC,
                                      blockIdx.x, blockIdx.y, blockIdx.z);
}

// ---- D1: X->f16 || Wq,Wk bf16-split || Wv transpose->f16 ----
__global__ __launch_bounds__(256) void prep_all(
    const float4* __restrict__ X, f16* __restrict__ Xf,
    const float* __restrict__ Wq, const float* __restrict__ Wk, const float* __restrict__ Wv,
    bf16* __restrict__ Wq_h, bf16* __restrict__ Wq_l,
    bf16* __restrict__ Wk_h, bf16* __restrict__ Wk_l,
    f16* __restrict__ Wvt_f)
{
    int b = blockIdx.x;
    if (b < 8192) {
        long long i = (long long)b * 256 + threadIdx.x;
        float4 v = X[i];
        f16x4 fv = {(f16)v.x, (f16)v.y, (f16)v.z, (f16)v.w};
        *(f16x4*)(Xf + 4 * i) = fv;
    } else if (b < 10240) {
        const int b2 = b - 8192;
        const float4* W = (const float4*)(b2 < 1024 ? Wq : Wk);
        bf16* hh = b2 < 1024 ? Wq_h : Wk_h;
        bf16* ll = b2 < 1024 ? Wq_l : Wk_l;
        long long i = (long long)(b2 & 1023) * 256 + threadIdx.x;
        float4 v = W[i];
        bf16 a0 = (bf16)v.x, a1 = (bf16)v.y, a2 = (bf16)v.z, a3 = (bf16)v.w;
        bf16x4 hv = {a0, a1, a2, a3};
        bf16x4 lv = {(bf16)(v.x - (float)a0), (bf16)(v.y - (float)a1),
                     (bf16)(v.z - (float)a2), (bf16)(v.w - (float)a3)};
        *(bf16x4*)(hh + 4 * i) = hv;
        *(bf16x4*)(ll + 4 * i) = lv;
    } else {
        const int b3 = b - 10240;
        __shared__ float t[32][33];
        const int bx = (b3 & 31) * 32, by = (b3 >> 5) * 32;
        const int tx = threadIdx.x & 31, ty = threadIdx.x >> 5;
#pragma unroll
        for (int i = 0; i < 32; i += 8)
            t[ty + i][tx] = Wv[(long long)(by + ty + i) * 1024 + bx + tx];
        __syncthreads();
#pragma unroll
        for (int i = 0; i < 32; i += 8) {
            long long o = (long long)(bx + ty + i) * 1024 + by + tx;
            Wvt_f[o] = (f16)t[tx][ty + i];
        }
    }
}

// ---- D5: row softmax fp32 -> f16, vectorized ----
__global__ __launch_bounds__(256) void softmax_f16(const float* __restrict__ S,
                                                   f16* __restrict__ P, int n)
{
    const long long row = blockIdx.x;
    const float4* p = (const float4*)(S + row * (long long)n);
    f16* q = P + row * (long long)n;
    const int tid = threadIdx.x;
    const int wv = tid >> 6, lane = tid & 63;

    float4 va = p[tid], vb = p[tid + 256];
    float v[8] = {va.x, va.y, va.z, va.w, vb.x, vb.y, vb.z, vb.w};
    float m = -3.4e38f;
#pragma unroll
    for (int i = 0; i < 8; i++) m = fmaxf(m, v[i]);
#pragma unroll
    for (int off = 32; off > 0; off >>= 1) m = fmaxf(m, __shfl_xor(m, off, 64));

    __shared__ float red[4];
    if (lane == 0) red[wv] = m;
    __syncthreads();
    m = fmaxf(fmaxf(red[0], red[1]), fmaxf(red[2], red[3]));

    float s = 0.f;
#pragma unroll
    for (int i = 0; i < 8; i++) { v[i] = __expf(v[i] - m); s += v[i]; }
#pragma unroll
    for (int off = 32; off > 0; off >>= 1) s += __shfl_xor(s, off, 64);
    __syncthreads();
    if (lane == 0) red[wv] = s;
    __syncthreads();
    s = red[0] + red[1] + red[2] + red[3];

    const float inv = 1.0f / s;
    f16x4 o0 = {(f16)(v[0] * inv), (f16)(v[1] * inv), (f16)(v[2] * inv), (f16)(v[3] * inv)};
    f16x4 o1 = {(f16)(v[4] * inv), (f16)(v[5] * inv), (f16)(v[6] * inv), (f16)(v[7] * inv)};
    *(f16x4*)(q + tid * 4) = o0;
    *(f16x4*)(q + 1024 + tid * 4) = o1;
}

extern "C" void kernel_launch(void* const* d_in, const int* in_sizes, int n_in,
                              void* d_out, int out_size, void* d_ws, size_t ws_size,
                              hipStream_t stream) {
    const float* X  = (const float*)d_in[0];   // [8192,1024]
    const float* Wq = (const float*)d_in[1];   // [1024,1024]
    const float* Wk = (const float*)d_in[2];
    const float* Wv = (const float*)d_in[3];
    float* out = (float*)d_out;                // [8192,1024]

    char* w = (char*)d_ws;
    const long long MB = 1024LL * 1024;
    f16*  Xf    = (f16*) (w + 0 * MB);     // 16 MB
    bf16* Wq_h  = (bf16*)(w + 16 * MB);    // 2 MB
    bf16* Wq_l  = (bf16*)(w + 18 * MB);
    bf16* Wk_h  = (bf16*)(w + 20 * MB);
    bf16* Wk_l  = (bf16*)(w + 22 * MB);
    f16*  Wvt_f = (f16*) (w + 24 * MB);    // 2 MB (transposed)
    f16*  Mt_f  = (f16*) (w + 26 * MB);    // 2 MB
    f16*  T     = (f16*) (w + 28 * MB);    // 16 MB [8192,1024]
    f16*  Vt    = (f16*) (w + 44 * MB);    // 16 MB [4][1024][2048]
    float* Sc   = (float*)(w + 60 * MB);   // 64 MB
    f16*  P     = (f16*) (w + 124 * MB);   // 32 MB -> ends 156 MB

    static int deep_ok = -1;
    if (deep_ok < 0) {
        auto* pSc = gemmd_k<0, 2>;
        auto* pPv = gemmd_k<0, 1>;
        hipError_t e1 = hipFuncSetAttribute(
            reinterpret_cast<const void*>(tv8d),
            hipFuncAttributeMaxDynamicSharedMemorySize, 131072);
        hipError_t e2 = hipFuncSetAttribute(
            reinterpret_cast<const void*>(pSc),
            hipFuncAttributeMaxDynamicSharedMemorySize, 131072);
        hipError_t e3 = hipFuncSetAttribute(
            reinterpret_cast<const void*>(pPv),
            hipFuncAttributeMaxDynamicSharedMemorySize, 98304);
        deep_ok = (e1 == hipSuccess && e2 == hipSuccess && e3 == hipSuccess) ? 1 : 0;
    }

    dim3 blk(256);

    // D1: prep
    prep_all<<<dim3(11264), blk, 0, stream>>>(
        (const float4*)X, Xf, Wq, Wk, Wv, Wq_h, Wq_l, Wk_h, Wk_l, Wvt_f);

    // D2: Mt = Wk_s Wq_s^T (split bf16, 3-MFMA) -> f16
    gemm_bt<bf16, true, 1, 32><<<dim3(8, 8, 1), blk, 32768, stream>>>(
        Wk_h, Wk_l, Wq_h, Wq_l, nullptr, Mt_f,
        1024, 1024, 1024, 1024, 0, 0, 0);

    if (deep_ok) {
        tv8d<<<dim3(8, 32), dim3(512), 131072, stream>>>(Xf, Mt_f, Wvt_f, T, Vt);
        gemmd_k<0, 2><<<dim3(8, 8, 4), dim3(512), 131072, stream>>>(
            T, Xf, Sc, nullptr, 1024, 1024, 1024, 2048,
            2048LL * 1024, 2048LL * 1024, 2048LL * 2048);
        softmax_f16<<<dim3(4 * 2048), blk, 0, stream>>>(Sc, P, 2048);
        gemmd_k<0, 1><<<dim3(4, 16, 4), dim3(512), 98304, stream>>>(
            P, Vt, out, nullptr, 2048, 2048, 2048, 1024,
            2048LL * 2048, 1024LL * 2048, 2048LL * 1024);
    } else {
        tv8<<<dim3(8, 32), dim3(512), 65536, stream>>>(Xf, Mt_f, Wvt_f, T, Vt);
        gemm8_k<0, 2><<<dim3(8, 8, 4), dim3(512), 65536, stream>>>(
            T, Xf, Sc, nullptr, 1024, 1024, 1024, 2048,
            2048LL * 1024, 2048LL * 1024, 2048LL * 2048);
        softmax_f16<<<dim3(4 * 2048), blk, 0, stream>>>(Sc, P, 2048);
        gemm8_k<0, 1><<<dim3(4, 16, 4), dim3(512), 49152, stream>>>(
            P, Vt, out, nullptr, 2048, 2048, 2048, 1024,
            2048LL * 2048, 1024LL * 2048, 2048LL * 1024);
    }
}